// Round 4
// baseline (2695.716 us; speedup 1.0000x reference)
//
#include <hip/hip_runtime.h>
#include <hip/hip_bf16.h>
#include <hip/hip_fp16.h>
#include <stdint.h>

#define FEATS   512
#define HIDDEN  64
#define CLASSES 16
#define EMB_DIM 7
#define ADJ_H   11
#define DEPTH   10

typedef __hip_bfloat16 bf16;
typedef __attribute__((ext_vector_type(8))) short short8;
typedef __attribute__((ext_vector_type(4))) float f32x4;

__device__ __forceinline__ float b2f(bf16 v) { return __bfloat162float(v); }

__device__ __forceinline__ float4 ld_half4(const __half* p) {
    uint2 rv = *(const uint2*)p;
    __half2 a = *(__half2*)&rv.x;
    __half2 b = *(__half2*)&rv.y;
    float2 fa = __half22float2(a);
    float2 fb = __half22float2(b);
    return make_float4(fa.x, fa.y, fb.x, fb.y);
}
__device__ __forceinline__ void st_half4(__half* p, float4 v) {
    __half2 a = __floats2half2_rn(v.x, v.y);
    __half2 b = __floats2half2_rn(v.z, v.w);
    uint2 rv;
    rv.x = *(unsigned*)&a;
    rv.y = *(unsigned*)&b;
    *(uint2*)p = rv;
}

// ---------------- dtype detect: 1 = bf16, 0 = f32 ----------------
__global__ void k_detect(const unsigned short* __restrict__ xs, int* __restrict__ flag) {
    __shared__ int cnt;
    if (threadIdx.x == 0) cnt = 0;
    __syncthreads();
    int c = 0;
    for (int i = threadIdx.x; i < 4096; i += 256) {
        unsigned e = (xs[i] >> 7) & 0xFFu;
        if (e >= 134u) c++;
    }
    atomicAdd(&cnt, c);
    __syncthreads();
    if (threadIdx.x == 0) *flag = (cnt < 64) ? 1 : 0;
}

// ---------------- degree ----------------
__global__ __launch_bounds__(256) void k_deg(const int* __restrict__ edges,
                                             int* __restrict__ deg, int E) {
    int e = blockIdx.x * 256 + threadIdx.x;
    if (e < E) atomicAdd(&deg[edges[E + e]], 1);
}

__global__ __launch_bounds__(256) void k_dinv(const int* __restrict__ deg,
                                              float* __restrict__ dinv, int n) {
    int i = blockIdx.x * 256 + threadIdx.x;
    if (i < n) {
        int d = deg[i];
        dinv[i] = (d > 0) ? rsqrtf((float)d) : 0.0f;
    }
}

// ---------------- exclusive scan ----------------
__global__ __launch_bounds__(256) void k_scan1(const int* __restrict__ deg,
                                               int* __restrict__ offs,
                                               int* __restrict__ bsum, int n) {
    __shared__ int ts[256];
    int t = threadIdx.x;
    int base = blockIdx.x * 1024 + t * 4;
    int v0 = (base + 0 < n) ? deg[base + 0] : 0;
    int v1 = (base + 1 < n) ? deg[base + 1] : 0;
    int v2 = (base + 2 < n) ? deg[base + 2] : 0;
    int v3 = (base + 3 < n) ? deg[base + 3] : 0;
    int tsum = v0 + v1 + v2 + v3;
    ts[t] = tsum;
    __syncthreads();
    for (int d = 1; d < 256; d <<= 1) {
        int add = (t >= d) ? ts[t - d] : 0;
        __syncthreads();
        ts[t] += add;
        __syncthreads();
    }
    int excl = ts[t] - tsum;
    if (base + 0 < n) offs[base + 0] = excl;
    if (base + 1 < n) offs[base + 1] = excl + v0;
    if (base + 2 < n) offs[base + 2] = excl + v0 + v1;
    if (base + 3 < n) offs[base + 3] = excl + v0 + v1 + v2;
    if (t == 255) bsum[blockIdx.x] = ts[255];
}

__global__ void k_scan2(const int* __restrict__ bsum, int* __restrict__ bpref,
                        int* __restrict__ offs, int nb, int n) {
    if (threadIdx.x == 0 && blockIdx.x == 0) {
        int run = 0;
        for (int i = 0; i < nb; ++i) { bpref[i] = run; run += bsum[i]; }
        offs[n] = run;
    }
}

__global__ __launch_bounds__(256) void k_scan3(int* __restrict__ offs,
                                               const int* __restrict__ bpref, int n) {
    int i = blockIdx.x * 256 + threadIdx.x;
    if (i < n) offs[i] += bpref[i >> 10];
}

// ---------------- CSR fill: pack (src:17b | w:15b fixed-point x16384) ----------------
__global__ __launch_bounds__(256) void k_fill(const int* __restrict__ edges,
                                              const int* __restrict__ offs,
                                              int* __restrict__ cursor,
                                              const float* __restrict__ dinv,
                                              unsigned* __restrict__ ew, int E) {
    int e = blockIdx.x * 256 + threadIdx.x;
    if (e < E) {
        int src = edges[e];
        int dst = edges[E + e];
        int pos = offs[dst] + atomicAdd(&cursor[dst], 1);
        float w = dinv[src] * dinv[dst];       // in [0, 1]
        int w15 = (int)(w * 16384.0f + 0.5f);
        if (w15 > 32767) w15 = 32767;
        ew[pos] = ((unsigned)src << 15) | (unsigned)w15;
    }
}

// ---------------- MLP constants (reads raw dtype via flag) ----------------
__global__ void k_mlpconst(const void* __restrict__ emb, const void* __restrict__ W_a1,
                           const void* __restrict__ b_a1, const void* __restrict__ W_a2,
                           const void* __restrict__ b_a2, const int* __restrict__ flag,
                           float* __restrict__ C) {
    int isbf = *flag;
    auto g = [&](const void* p, int i) -> float {
        return isbf ? b2f(((const bf16*)p)[i]) : ((const float*)p)[i];
    };
    int j = threadIdx.x;
    if (j < ADJ_H) {
        float c = g(b_a1, j);
        for (int k = 0; k < EMB_DIM; ++k)
            c += g(emb, k) * g(W_a1, (2 + k) * ADJ_H + j);
        C[j]      = c;
        C[11 + j] = g(W_a1, 0 * ADJ_H + j);
        C[22 + j] = g(W_a1, 1 * ADJ_H + j);
        C[33 + j] = g(W_a2, j);
    }
    if (j == 0) C[44] = g(b_a2, 0);
}

// ---------------- MFMA GEMM: h = x @ W + b -> fp16 out in [slice][node][16] layout ----
__global__ __launch_bounds__(256) void k_gemm_mfma(const void* __restrict__ xraw,
                                                   const int* __restrict__ flag,
                                                   const void* __restrict__ Wraw,
                                                   const void* __restrict__ braw,
                                                   __half* __restrict__ out, int n,
                                                   int nstride) {
    __shared__ short Wt[64 * 520];
    int t = threadIdx.x;
    int isbf = *flag;
    if (isbf) {
        const unsigned short* wr = (const unsigned short*)Wraw;
        for (int e = t; e < FEATS * HIDDEN; e += 256)
            Wt[(e & 63) * 520 + (e >> 6)] = (short)wr[e];
    } else {
        const float* wr = (const float*)Wraw;
        for (int e = t; e < FEATS * HIDDEN; e += 256)
            Wt[(e & 63) * 520 + (e >> 6)] = (short)(__float_as_uint(wr[e]) >> 16);
    }
    __syncthreads();

    int wv = t >> 6;
    int lane = t & 63;
    int quad = lane >> 4, l16 = lane & 15;
    int rowbase = blockIdx.x * 256 + wv * 64;

    f32x4 acc[4][4];
    #pragma unroll
    for (int a = 0; a < 4; ++a)
        #pragma unroll
        for (int b = 0; b < 4; ++b)
            acc[a][b] = (f32x4){0.f, 0.f, 0.f, 0.f};

    if (isbf) {
        const short* x = (const short*)xraw;
        for (int ks = 0; ks < 16; ++ks) {
            short8 bfr[4];
            #pragma unroll
            for (int nt = 0; nt < 4; ++nt)
                bfr[nt] = *(const short8*)&Wt[(nt * 16 + l16) * 520 + ks * 32 + quad * 8];
            #pragma unroll
            for (int rt = 0; rt < 4; ++rt) {
                int arow = rowbase + rt * 16 + l16;
                if (arow >= n) arow = n - 1;
                short8 a = *(const short8*)(x + (size_t)arow * FEATS + ks * 32 + quad * 8);
                #pragma unroll
                for (int nt = 0; nt < 4; ++nt)
                    acc[rt][nt] = __builtin_amdgcn_mfma_f32_16x16x32_bf16(a, bfr[nt], acc[rt][nt], 0, 0, 0);
            }
        }
    } else {
        const float* x = (const float*)xraw;
        for (int ks = 0; ks < 16; ++ks) {
            short8 bfr[4];
            #pragma unroll
            for (int nt = 0; nt < 4; ++nt)
                bfr[nt] = *(const short8*)&Wt[(nt * 16 + l16) * 520 + ks * 32 + quad * 8];
            #pragma unroll
            for (int rt = 0; rt < 4; ++rt) {
                int arow = rowbase + rt * 16 + l16;
                if (arow >= n) arow = n - 1;
                const float* ap = x + (size_t)arow * FEATS + ks * 32 + quad * 8;
                short8 a;
                #pragma unroll
                for (int j = 0; j < 8; ++j)
                    a[j] = (short)(__float_as_uint(ap[j]) >> 16);
                #pragma unroll
                for (int nt = 0; nt < 4; ++nt)
                    acc[rt][nt] = __builtin_amdgcn_mfma_f32_16x16x32_bf16(a, bfr[nt], acc[rt][nt], 0, 0, 0);
            }
        }
    }

    float bias[4];
    #pragma unroll
    for (int nt = 0; nt < 4; ++nt)
        bias[nt] = isbf ? b2f(((const bf16*)braw)[nt * 16 + l16])
                        : ((const float*)braw)[nt * 16 + l16];

    // out layout: [slice=nt][node][16]; col-within-slice = l16
    #pragma unroll
    for (int rt = 0; rt < 4; ++rt)
        #pragma unroll
        for (int nt = 0; nt < 4; ++nt) {
            #pragma unroll
            for (int r = 0; r < 4; ++r) {
                int grow = rowbase + rt * 16 + quad * 4 + r;
                if (grow < n)
                    out[(size_t)nt * nstride + (size_t)grow * 16 + l16] =
                        __float2half(acc[rt][nt][r] + bias[nt]);
            }
        }
}

// ---------------- conv: channel-sliced, XCD-pinned ----------------
// h layout [slice][node][16] fp16. slice = blockIdx.x & 3 -> stable per-XCD
// (bid%8 round-robin => XCDs {s, s+4} own slice s; 3.2 MB slice fits 4 MiB L2).
// Wave: 16 edges in flight (4 lanes/edge, 4 fp16 channels/lane), xor-reduce.
__global__ __launch_bounds__(256) void k_conv(const int* __restrict__ offs,
                                              const unsigned* __restrict__ ew,
                                              const __half* __restrict__ hin,
                                              const __half* __restrict__ h0,
                                              __half* __restrict__ hout,
                                              int n, int nstride) {
    int bid = blockIdx.x;
    int slice = bid & 3;
    int node = (bid >> 2) * 4 + (threadIdx.x >> 6);
    if (node >= n) return;
    int lane = threadIdx.x & 63;
    int eg = lane >> 2;           // 16 edge groups
    int cq = lane & 3;            // 4 fp16 channels per lane
    const __half* hs = hin + (size_t)slice * nstride;
    int start = offs[node], end = offs[node + 1];
    float4 acc = make_float4(0.f, 0.f, 0.f, 0.f);
    for (int p = start + eg; p < end; p += 16) {
        unsigned u = ew[p];
        int src = (int)(u >> 15);
        float w = (float)(u & 0x7FFFu) * (1.0f / 16384.0f);
        float4 v = ld_half4(hs + (size_t)src * 16 + cq * 4);
        acc.x += w * v.x; acc.y += w * v.y; acc.z += w * v.z; acc.w += w * v.w;
    }
    // reduce over the 16 edge groups (xor 4, 8, 16, 32 keeps cq fixed)
    acc.x += __shfl_xor(acc.x, 4);  acc.y += __shfl_xor(acc.y, 4);
    acc.z += __shfl_xor(acc.z, 4);  acc.w += __shfl_xor(acc.w, 4);
    acc.x += __shfl_xor(acc.x, 8);  acc.y += __shfl_xor(acc.y, 8);
    acc.z += __shfl_xor(acc.z, 8);  acc.w += __shfl_xor(acc.w, 8);
    acc.x += __shfl_xor(acc.x, 16); acc.y += __shfl_xor(acc.y, 16);
    acc.z += __shfl_xor(acc.z, 16); acc.w += __shfl_xor(acc.w, 16);
    acc.x += __shfl_xor(acc.x, 32); acc.y += __shfl_xor(acc.y, 32);
    acc.z += __shfl_xor(acc.z, 32); acc.w += __shfl_xor(acc.w, 32);
    if (eg == 0) {
        size_t o = (size_t)slice * nstride + (size_t)node * 16 + cq * 4;
        float4 h0v = ld_half4(h0 + o);
        float4 r;
        r.x = 0.9f * acc.x + 0.1f * h0v.x;
        r.y = 0.9f * acc.y + 0.1f * h0v.y;
        r.z = 0.9f * acc.z + 0.1f * h0v.z;
        r.w = 0.9f * acc.w + 0.1f * h0v.w;
        st_half4(hout + o, r);
    }
}

// ---------------- elementwise edge-MLP (layout-agnostic, in-place on h0) ----------------
__global__ __launch_bounds__(256) void k_mlp(__half* __restrict__ h0io,
                                             const __half* __restrict__ hc,
                                             const float* __restrict__ C, int total2) {
    int i = blockIdx.x * 256 + threadIdx.x;
    if (i >= total2) return;
    float2 hv  = __half22float2(((const __half2*)hc)[i]);
    float2 h0v = __half22float2(((const __half2*)h0io)[i]);
    float sx = C[44], sy = C[44];
    #pragma unroll
    for (int j = 0; j < ADJ_H; ++j) {
        float bj = C[j], wh = C[11 + j], w0 = C[22 + j], wo = C[33 + j];
        float zx = bj + hv.x * wh + h0v.x * w0;
        float zy = bj + hv.y * wh + h0v.y * w0;
        zx = (zx > 0.f) ? zx : 0.01f * zx;
        zy = (zy > 0.f) ? zy : 0.01f * zy;
        sx += zx * wo;
        sy += zy * wo;
    }
    ((__half2*)h0io)[i] = __floats2half2_rn(0.5f * sx, 0.5f * sy);
}

// ---------------- classifier (reads slice layout + raw weights) ----------------
__global__ __launch_bounds__(256) void k_cls(const __half* __restrict__ h,
                                             const void* __restrict__ Wcraw,
                                             const void* __restrict__ bcraw,
                                             void* __restrict__ outraw,
                                             const int* __restrict__ flag,
                                             int n, int nstride) {
    __shared__ float hs[64][65];
    __shared__ float ws[64 * 16];
    __shared__ float bs[16];
    int t = threadIdx.x;
    int base = blockIdx.x * 64;
    int isbf = *flag;
    for (int it = 0; it < 16; ++it) {
        int e = it * 256 + t;
        int rr = e >> 6, cc = e & 63;
        int g = base + rr;
        hs[rr][cc] = (g < n)
            ? __half2float(h[(size_t)(cc >> 4) * nstride + (size_t)g * 16 + (cc & 15)])
            : 0.f;
    }
    for (int it = 0; it < 4; ++it) {
        int e = it * 256 + t;
        ws[e] = isbf ? b2f(((const bf16*)Wcraw)[e]) : ((const float*)Wcraw)[e];
    }
    if (t < 16) bs[t] = isbf ? b2f(((const bf16*)bcraw)[t]) : ((const float*)bcraw)[t];
    __syncthreads();
    for (int q = 0; q < 4; ++q) {
        int e = q * 256 + t;
        int node = e >> 4, cls = e & 15;
        float acc = bs[cls];
        #pragma unroll 8
        for (int k = 0; k < HIDDEN; ++k)
            acc += hs[node][k] * ws[k * 16 + cls];
        int g = base + node;
        if (g < n) {
            size_t oi = (size_t)g * CLASSES + cls;
            if (isbf) ((bf16*)outraw)[oi] = __float2bfloat16(acc);
            else      ((float*)outraw)[oi] = acc;
        }
    }
}

extern "C" void kernel_launch(void* const* d_in, const int* in_sizes, int n_in,
                              void* d_out, int out_size, void* d_ws, size_t ws_size,
                              hipStream_t stream) {
    const void* x     = d_in[0];
    const int*  edges = (const int*)d_in[1];
    const void* W_dim = d_in[2];
    const void* b_dim = d_in[3];
    const void* emb   = d_in[4];
    const void* W_a1  = d_in[5];
    const void* b_a1  = d_in[6];
    const void* W_a2  = d_in[7];
    const void* b_a2  = d_in[8];
    const void* Wcls  = d_in[9];
    const void* bcls  = d_in[10];

    const int n = in_sizes[0] / FEATS;     // 100000
    const int E = in_sizes[1] / 2;         // 1600000
    const int nstride = n * 16;            // elements per channel slice

    char* w = (char*)d_ws;
    size_t off = 0;
    auto alloc = [&](size_t bytes) -> void* {
        void* p = w + off;
        off = (off + bytes + 255) & ~(size_t)255;
        return p;
    };
    int*      deg    = (int*)     alloc((size_t)n * 4);
    int*      cursor = (int*)     alloc((size_t)n * 4);
    int*      offs   = (int*)     alloc((size_t)(n + 1) * 4);
    float*    dinv   = (float*)   alloc((size_t)n * 4);
    int*      bsum   = (int*)     alloc(4096 * 4);
    int*      bpref  = (int*)     alloc(4096 * 4);
    unsigned* ew     = (unsigned*)alloc((size_t)E * 4);
    float*    consts = (float*)   alloc(64 * 4);
    int*      flag   = (int*)     alloc(256);
    __half*   buf0   = (__half*)  alloc((size_t)n * HIDDEN * 2);
    __half*   bufA   = (__half*)  alloc((size_t)n * HIDDEN * 2);
    __half*   bufB   = (__half*)  alloc((size_t)n * HIDDEN * 2);

    int gE = (E + 255) / 256;
    int gN = (n + 255) / 256;
    int nb = (n + 1023) / 1024;
    int gConv = ((n + 3) / 4) * 4;   // 4 slices x node-blocks of 4 nodes

    hipMemsetAsync(deg, 0, ((char*)cursor - (char*)deg) + (size_t)n * 4, stream);

    k_detect<<<1, 256, 0, stream>>>((const unsigned short*)x, flag);

    k_deg  <<<gE, 256, 0, stream>>>(edges, deg, E);
    k_dinv <<<gN, 256, 0, stream>>>(deg, dinv, n);
    k_scan1<<<nb, 256, 0, stream>>>(deg, offs, bsum, n);
    k_scan2<<<1, 64, 0, stream>>>(bsum, bpref, offs, nb, n);
    k_scan3<<<gN, 256, 0, stream>>>(offs, bpref, n);
    k_fill <<<gE, 256, 0, stream>>>(edges, offs, cursor, dinv, ew, E);

    k_mlpconst<<<1, 64, 0, stream>>>(emb, W_a1, b_a1, W_a2, b_a2, flag, consts);

    k_gemm_mfma<<<(n + 255) / 256, 256, 0, stream>>>(x, flag, W_dim, b_dim, buf0, n, nstride);

    const __half* hin = buf0;
    for (int i = 0; i < DEPTH; ++i) {
        __half* ho = (i & 1) ? bufB : bufA;
        k_conv<<<gConv, 256, 0, stream>>>(offs, ew, hin, buf0, ho, n, nstride);
        hin = ho;
    }
    k_mlp<<<(n * (HIDDEN / 2) + 255) / 256, 256, 0, stream>>>(buf0, hin, consts, n * (HIDDEN / 2));

    hin = buf0;
    for (int i = 0; i < DEPTH; ++i) {
        __half* ho = (i & 1) ? bufB : bufA;
        k_conv<<<gConv, 256, 0, stream>>>(offs, ew, hin, buf0, ho, n, nstride);
        hin = ho;
    }
    k_cls<<<(n + 63) / 64, 256, 0, stream>>>(hin, Wcls, bcls, d_out, flag, n, nstride);
}

// Round 5
// 1300.238 us; speedup vs baseline: 2.0732x; 2.0732x over previous
//
#include <hip/hip_runtime.h>
#include <hip/hip_bf16.h>
#include <hip/hip_fp16.h>
#include <stdint.h>

#define FEATS   512
#define HIDDEN  64
#define CLASSES 16
#define EMB_DIM 7
#define ADJ_H   11
#define DEPTH   10

typedef __hip_bfloat16 bf16;
typedef __attribute__((ext_vector_type(8))) short short8;
typedef __attribute__((ext_vector_type(4))) float f32x4;

__device__ __forceinline__ float b2f(bf16 v) { return __bfloat162float(v); }

// ---------------- dtype detect: 1 = bf16, 0 = f32 ----------------
__global__ void k_detect(const unsigned short* __restrict__ xs, int* __restrict__ flag) {
    __shared__ int cnt;
    if (threadIdx.x == 0) cnt = 0;
    __syncthreads();
    int c = 0;
    for (int i = threadIdx.x; i < 4096; i += 256) {
        unsigned e = (xs[i] >> 7) & 0xFFu;
        if (e >= 134u) c++;
    }
    atomicAdd(&cnt, c);
    __syncthreads();
    if (threadIdx.x == 0) *flag = (cnt < 64) ? 1 : 0;
}

// ---------------- degree ----------------
__global__ __launch_bounds__(256) void k_deg(const int* __restrict__ edges,
                                             int* __restrict__ deg, int E) {
    int e = blockIdx.x * 256 + threadIdx.x;
    if (e < E) atomicAdd(&deg[edges[E + e]], 1);
}

// ---------------- exclusive scan ----------------
__global__ __launch_bounds__(256) void k_scan1(const int* __restrict__ deg,
                                               int* __restrict__ offs,
                                               int* __restrict__ bsum, int n) {
    __shared__ int ts[256];
    int t = threadIdx.x;
    int base = blockIdx.x * 1024 + t * 4;
    int v0 = (base + 0 < n) ? deg[base + 0] : 0;
    int v1 = (base + 1 < n) ? deg[base + 1] : 0;
    int v2 = (base + 2 < n) ? deg[base + 2] : 0;
    int v3 = (base + 3 < n) ? deg[base + 3] : 0;
    int tsum = v0 + v1 + v2 + v3;
    ts[t] = tsum;
    __syncthreads();
    for (int d = 1; d < 256; d <<= 1) {
        int add = (t >= d) ? ts[t - d] : 0;
        __syncthreads();
        ts[t] += add;
        __syncthreads();
    }
    int excl = ts[t] - tsum;
    if (base + 0 < n) offs[base + 0] = excl;
    if (base + 1 < n) offs[base + 1] = excl + v0;
    if (base + 2 < n) offs[base + 2] = excl + v0 + v1;
    if (base + 3 < n) offs[base + 3] = excl + v0 + v1 + v2;
    if (t == 255) bsum[blockIdx.x] = ts[255];
}

__global__ void k_scan2(const int* __restrict__ bsum, int* __restrict__ bpref,
                        int* __restrict__ offs, int nb, int n) {
    if (threadIdx.x == 0 && blockIdx.x == 0) {
        int run = 0;
        for (int i = 0; i < nb; ++i) { bpref[i] = run; run += bsum[i]; }
        offs[n] = run;
    }
}

__global__ __launch_bounds__(256) void k_scan3(int* __restrict__ offs,
                                               const int* __restrict__ bpref, int n) {
    int i = blockIdx.x * 256 + threadIdx.x;
    if (i < n) offs[i] += bpref[i >> 10];
}

// ---------------- CSR fill: pack (src:17b | w:15b fixed-point x16384) ----------------
__global__ __launch_bounds__(256) void k_fill(const int* __restrict__ edges,
                                              const int* __restrict__ offs,
                                              int* __restrict__ cursor,
                                              const int* __restrict__ deg,
                                              unsigned* __restrict__ ew, int E) {
    int e = blockIdx.x * 256 + threadIdx.x;
    if (e < E) {
        int src = edges[e];
        int dst = edges[E + e];
        int pos = offs[dst] + atomicAdd(&cursor[dst], 1);
        int ds = deg[src], dd = deg[dst];
        float w = (ds > 0 ? rsqrtf((float)ds) : 0.f) * (dd > 0 ? rsqrtf((float)dd) : 0.f);
        int w15 = (int)(w * 16384.0f + 0.5f);
        if (w15 > 32767) w15 = 32767;
        ew[pos] = ((unsigned)src << 15) | (unsigned)w15;
    }
}

// ---------------- MLP constants (reads raw dtype via flag) ----------------
__global__ void k_mlpconst(const void* __restrict__ emb, const void* __restrict__ W_a1,
                           const void* __restrict__ b_a1, const void* __restrict__ W_a2,
                           const void* __restrict__ b_a2, const int* __restrict__ flag,
                           float* __restrict__ C) {
    int isbf = *flag;
    auto g = [&](const void* p, int i) -> float {
        return isbf ? b2f(((const bf16*)p)[i]) : ((const float*)p)[i];
    };
    int j = threadIdx.x;
    if (j < ADJ_H) {
        float c = g(b_a1, j);
        for (int k = 0; k < EMB_DIM; ++k)
            c += g(emb, k) * g(W_a1, (2 + k) * ADJ_H + j);
        C[j]      = c;
        C[11 + j] = g(W_a1, 0 * ADJ_H + j);
        C[22 + j] = g(W_a1, 1 * ADJ_H + j);
        C[33 + j] = g(W_a2, j);
    }
    if (j == 0) C[44] = g(b_a2, 0);
}

// ---------------- MFMA GEMM: h = x @ W + b -> fp16 [node][64] ----------------
__global__ __launch_bounds__(256) void k_gemm_mfma(const void* __restrict__ xraw,
                                                   const int* __restrict__ flag,
                                                   const void* __restrict__ Wraw,
                                                   const void* __restrict__ braw,
                                                   __half* __restrict__ out, int n) {
    __shared__ short Wt[64 * 520];
    int t = threadIdx.x;
    int isbf = *flag;
    if (isbf) {
        const unsigned short* wr = (const unsigned short*)Wraw;
        for (int e = t; e < FEATS * HIDDEN; e += 256)
            Wt[(e & 63) * 520 + (e >> 6)] = (short)wr[e];
    } else {
        const float* wr = (const float*)Wraw;
        for (int e = t; e < FEATS * HIDDEN; e += 256)
            Wt[(e & 63) * 520 + (e >> 6)] = (short)(__float_as_uint(wr[e]) >> 16);
    }
    __syncthreads();

    int wv = t >> 6;
    int lane = t & 63;
    int quad = lane >> 4, l16 = lane & 15;
    int rowbase = blockIdx.x * 256 + wv * 64;

    f32x4 acc[4][4];
    #pragma unroll
    for (int a = 0; a < 4; ++a)
        #pragma unroll
        for (int b = 0; b < 4; ++b)
            acc[a][b] = (f32x4){0.f, 0.f, 0.f, 0.f};

    if (isbf) {
        const short* x = (const short*)xraw;
        for (int ks = 0; ks < 16; ++ks) {
            short8 bfr[4];
            #pragma unroll
            for (int nt = 0; nt < 4; ++nt)
                bfr[nt] = *(const short8*)&Wt[(nt * 16 + l16) * 520 + ks * 32 + quad * 8];
            #pragma unroll
            for (int rt = 0; rt < 4; ++rt) {
                int arow = rowbase + rt * 16 + l16;
                if (arow >= n) arow = n - 1;
                short8 a = *(const short8*)(x + (size_t)arow * FEATS + ks * 32 + quad * 8);
                #pragma unroll
                for (int nt = 0; nt < 4; ++nt)
                    acc[rt][nt] = __builtin_amdgcn_mfma_f32_16x16x32_bf16(a, bfr[nt], acc[rt][nt], 0, 0, 0);
            }
        }
    } else {
        const float* x = (const float*)xraw;
        for (int ks = 0; ks < 16; ++ks) {
            short8 bfr[4];
            #pragma unroll
            for (int nt = 0; nt < 4; ++nt)
                bfr[nt] = *(const short8*)&Wt[(nt * 16 + l16) * 520 + ks * 32 + quad * 8];
            #pragma unroll
            for (int rt = 0; rt < 4; ++rt) {
                int arow = rowbase + rt * 16 + l16;
                if (arow >= n) arow = n - 1;
                const float* ap = x + (size_t)arow * FEATS + ks * 32 + quad * 8;
                short8 a;
                #pragma unroll
                for (int j = 0; j < 8; ++j)
                    a[j] = (short)(__float_as_uint(ap[j]) >> 16);
                #pragma unroll
                for (int nt = 0; nt < 4; ++nt)
                    acc[rt][nt] = __builtin_amdgcn_mfma_f32_16x16x32_bf16(a, bfr[nt], acc[rt][nt], 0, 0, 0);
            }
        }
    }

    float bias[4];
    #pragma unroll
    for (int nt = 0; nt < 4; ++nt)
        bias[nt] = isbf ? b2f(((const bf16*)braw)[nt * 16 + l16])
                        : ((const float*)braw)[nt * 16 + l16];

    #pragma unroll
    for (int rt = 0; rt < 4; ++rt)
        #pragma unroll
        for (int nt = 0; nt < 4; ++nt) {
            #pragma unroll
            for (int r = 0; r < 4; ++r) {
                int grow = rowbase + rt * 16 + quad * 4 + r;
                if (grow < n)
                    out[(size_t)grow * HIDDEN + nt * 16 + l16] =
                        __float2half(acc[rt][nt][r] + bias[nt]);
            }
        }
}

// ---------------- conv: 2 nodes/wave, 8 groups x 8 lanes x 16 B ----------------
// hout = 0.9 * A@hin + 0.1 * h0. Per wave: nodes nA=2w, nB=2w+1. Each group
// handles every-8th edge; lane loads 8 fp16 channels (dwordx4). Two always-
// full independent load chains (A and B) per iteration. xor-reduce 8/16/32.
__global__ __launch_bounds__(256) void k_conv(const int* __restrict__ offs,
                                              const unsigned* __restrict__ ew,
                                              const __half* __restrict__ hin,
                                              const __half* __restrict__ h0,
                                              __half* __restrict__ hout, int n) {
    int wv = (blockIdx.x * 256 + threadIdx.x) >> 6;
    int nA = wv * 2;
    if (nA >= n) return;
    int nB = nA + 1;
    bool hasB = (nB < n);
    int lane = threadIdx.x & 63;
    int eg = lane >> 3;
    int li = lane & 7;
    int sA = offs[nA], eA = offs[nA + 1];
    int sB = hasB ? offs[nB] : 0;
    int eB = hasB ? offs[nB + 1] : 0;

    float4 a0 = make_float4(0.f,0.f,0.f,0.f), a1 = make_float4(0.f,0.f,0.f,0.f);
    float4 b0 = make_float4(0.f,0.f,0.f,0.f), b1 = make_float4(0.f,0.f,0.f,0.f);

    int pA = sA + eg, pB = sB + eg;
    while (pA < eA || pB < eB) {
        bool vA = pA < eA, vB = pB < eB;
        unsigned uA = 0, uB = 0;
        uint4 rA = make_uint4(0,0,0,0), rB = make_uint4(0,0,0,0);
        if (vA) {
            uA = ew[pA];
            rA = *(const uint4*)(hin + (size_t)(uA >> 15) * HIDDEN + li * 8);
        }
        if (vB) {
            uB = ew[pB];
            rB = *(const uint4*)(hin + (size_t)(uB >> 15) * HIDDEN + li * 8);
        }
        if (vA) {
            float w = (float)(uA & 0x7FFFu) * (1.0f / 16384.0f);
            float2 f0 = __half22float2(*(__half2*)&rA.x);
            float2 f1 = __half22float2(*(__half2*)&rA.y);
            float2 f2 = __half22float2(*(__half2*)&rA.z);
            float2 f3 = __half22float2(*(__half2*)&rA.w);
            a0.x += w*f0.x; a0.y += w*f0.y; a0.z += w*f1.x; a0.w += w*f1.y;
            a1.x += w*f2.x; a1.y += w*f2.y; a1.z += w*f3.x; a1.w += w*f3.y;
            pA += 8;
        }
        if (vB) {
            float w = (float)(uB & 0x7FFFu) * (1.0f / 16384.0f);
            float2 f0 = __half22float2(*(__half2*)&rB.x);
            float2 f1 = __half22float2(*(__half2*)&rB.y);
            float2 f2 = __half22float2(*(__half2*)&rB.z);
            float2 f3 = __half22float2(*(__half2*)&rB.w);
            b0.x += w*f0.x; b0.y += w*f0.y; b0.z += w*f1.x; b0.w += w*f1.y;
            b1.x += w*f2.x; b1.y += w*f2.y; b1.z += w*f3.x; b1.w += w*f3.y;
            pB += 8;
        }
    }

    // reduce across the 8 edge groups (lanes differing in bits 3..5)
    #pragma unroll
    for (int d = 8; d <= 32; d <<= 1) {
        a0.x += __shfl_xor(a0.x, d); a0.y += __shfl_xor(a0.y, d);
        a0.z += __shfl_xor(a0.z, d); a0.w += __shfl_xor(a0.w, d);
        a1.x += __shfl_xor(a1.x, d); a1.y += __shfl_xor(a1.y, d);
        a1.z += __shfl_xor(a1.z, d); a1.w += __shfl_xor(a1.w, d);
        b0.x += __shfl_xor(b0.x, d); b0.y += __shfl_xor(b0.y, d);
        b0.z += __shfl_xor(b0.z, d); b0.w += __shfl_xor(b0.w, d);
        b1.x += __shfl_xor(b1.x, d); b1.y += __shfl_xor(b1.y, d);
        b1.z += __shfl_xor(b1.z, d); b1.w += __shfl_xor(b1.w, d);
    }

    // lanes 0-7 store node A, lanes 8-15 store node B (contiguous 256 B)
    if (eg < 2 && (eg == 0 || hasB)) {
        int node = (eg == 0) ? nA : nB;
        float4 c0 = (eg == 0) ? a0 : b0;
        float4 c1 = (eg == 0) ? a1 : b1;
        size_t o = (size_t)node * HIDDEN + li * 8;
        uint4 hv = *(const uint4*)(h0 + o);
        float2 g0 = __half22float2(*(__half2*)&hv.x);
        float2 g1 = __half22float2(*(__half2*)&hv.y);
        float2 g2 = __half22float2(*(__half2*)&hv.z);
        float2 g3 = __half22float2(*(__half2*)&hv.w);
        __half2 o0 = __floats2half2_rn(0.9f*c0.x + 0.1f*g0.x, 0.9f*c0.y + 0.1f*g0.y);
        __half2 o1 = __floats2half2_rn(0.9f*c0.z + 0.1f*g1.x, 0.9f*c0.w + 0.1f*g1.y);
        __half2 o2 = __floats2half2_rn(0.9f*c1.x + 0.1f*g2.x, 0.9f*c1.y + 0.1f*g2.y);
        __half2 o3 = __floats2half2_rn(0.9f*c1.z + 0.1f*g3.x, 0.9f*c1.w + 0.1f*g3.y);
        uint4 ov;
        ov.x = *(unsigned*)&o0; ov.y = *(unsigned*)&o1;
        ov.z = *(unsigned*)&o2; ov.w = *(unsigned*)&o3;
        *(uint4*)(hout + o) = ov;
    }
}

// ---------------- elementwise edge-MLP (in-place on h0) ----------------
__global__ __launch_bounds__(256) void k_mlp(__half* __restrict__ h0io,
                                             const __half* __restrict__ hc,
                                             const float* __restrict__ C, int total2) {
    int i = blockIdx.x * 256 + threadIdx.x;
    if (i >= total2) return;
    float2 hv  = __half22float2(((const __half2*)hc)[i]);
    float2 h0v = __half22float2(((const __half2*)h0io)[i]);
    float sx = C[44], sy = C[44];
    #pragma unroll
    for (int j = 0; j < ADJ_H; ++j) {
        float bj = C[j], wh = C[11 + j], w0 = C[22 + j], wo = C[33 + j];
        float zx = bj + hv.x * wh + h0v.x * w0;
        float zy = bj + hv.y * wh + h0v.y * w0;
        zx = (zx > 0.f) ? zx : 0.01f * zx;
        zy = (zy > 0.f) ? zy : 0.01f * zy;
        sx += zx * wo;
        sy += zy * wo;
    }
    ((__half2*)h0io)[i] = __floats2half2_rn(0.5f * sx, 0.5f * sy);
}

// ---------------- classifier ----------------
__global__ __launch_bounds__(256) void k_cls(const __half* __restrict__ h,
                                             const void* __restrict__ Wcraw,
                                             const void* __restrict__ bcraw,
                                             void* __restrict__ outraw,
                                             const int* __restrict__ flag, int n) {
    __shared__ float hs[64][65];
    __shared__ float ws[64 * 16];
    __shared__ float bs[16];
    int t = threadIdx.x;
    int base = blockIdx.x * 64;
    int isbf = *flag;
    for (int it = 0; it < 16; ++it) {
        int e = it * 256 + t;
        int rr = e >> 6, cc = e & 63;
        int g = base + rr;
        hs[rr][cc] = (g < n) ? __half2float(h[(size_t)g * HIDDEN + cc]) : 0.f;
    }
    for (int it = 0; it < 4; ++it) {
        int e = it * 256 + t;
        ws[e] = isbf ? b2f(((const bf16*)Wcraw)[e]) : ((const float*)Wcraw)[e];
    }
    if (t < 16) bs[t] = isbf ? b2f(((const bf16*)bcraw)[t]) : ((const float*)bcraw)[t];
    __syncthreads();
    for (int q = 0; q < 4; ++q) {
        int e = q * 256 + t;
        int node = e >> 4, cls = e & 15;
        float acc = bs[cls];
        #pragma unroll 8
        for (int k = 0; k < HIDDEN; ++k)
            acc += hs[node][k] * ws[k * 16 + cls];
        int g = base + node;
        if (g < n) {
            size_t oi = (size_t)g * CLASSES + cls;
            if (isbf) ((bf16*)outraw)[oi] = __float2bfloat16(acc);
            else      ((float*)outraw)[oi] = acc;
        }
    }
}

extern "C" void kernel_launch(void* const* d_in, const int* in_sizes, int n_in,
                              void* d_out, int out_size, void* d_ws, size_t ws_size,
                              hipStream_t stream) {
    const void* x     = d_in[0];
    const int*  edges = (const int*)d_in[1];
    const void* W_dim = d_in[2];
    const void* b_dim = d_in[3];
    const void* emb   = d_in[4];
    const void* W_a1  = d_in[5];
    const void* b_a1  = d_in[6];
    const void* W_a2  = d_in[7];
    const void* b_a2  = d_in[8];
    const void* Wcls  = d_in[9];
    const void* bcls  = d_in[10];

    const int n = in_sizes[0] / FEATS;     // 100000
    const int E = in_sizes[1] / 2;         // 1600000

    char* w = (char*)d_ws;
    size_t off = 0;
    auto alloc = [&](size_t bytes) -> void* {
        void* p = w + off;
        off = (off + bytes + 255) & ~(size_t)255;
        return p;
    };
    int*      deg    = (int*)     alloc((size_t)n * 4);
    int*      cursor = (int*)     alloc((size_t)n * 4);
    int*      offs   = (int*)     alloc((size_t)(n + 1) * 4);
    int*      bsum   = (int*)     alloc(4096 * 4);
    int*      bpref  = (int*)     alloc(4096 * 4);
    unsigned* ew     = (unsigned*)alloc((size_t)E * 4);
    float*    consts = (float*)   alloc(64 * 4);
    int*      flag   = (int*)     alloc(256);
    __half*   buf0   = (__half*)  alloc((size_t)n * HIDDEN * 2);
    __half*   bufA   = (__half*)  alloc((size_t)n * HIDDEN * 2);
    __half*   bufB   = (__half*)  alloc((size_t)n * HIDDEN * 2);

    int gE = (E + 255) / 256;
    int gN = (n + 255) / 256;
    int nb = (n + 1023) / 1024;
    int gConv = (n + 7) / 8;   // 4 waves/block, 2 nodes/wave

    hipMemsetAsync(deg, 0, ((char*)cursor - (char*)deg) + (size_t)n * 4, stream);

    k_detect<<<1, 256, 0, stream>>>((const unsigned short*)x, flag);

    k_deg  <<<gE, 256, 0, stream>>>(edges, deg, E);
    k_scan1<<<nb, 256, 0, stream>>>(deg, offs, bsum, n);
    k_scan2<<<1, 64, 0, stream>>>(bsum, bpref, offs, nb, n);
    k_scan3<<<gN, 256, 0, stream>>>(offs, bpref, n);
    k_fill <<<gE, 256, 0, stream>>>(edges, offs, cursor, deg, ew, E);

    k_mlpconst<<<1, 64, 0, stream>>>(emb, W_a1, b_a1, W_a2, b_a2, flag, consts);

    k_gemm_mfma<<<(n + 255) / 256, 256, 0, stream>>>(x, flag, W_dim, b_dim, buf0, n);

    const __half* hin = buf0;
    for (int i = 0; i < DEPTH; ++i) {
        __half* ho = (i & 1) ? bufB : bufA;
        k_conv<<<gConv, 256, 0, stream>>>(offs, ew, hin, buf0, ho, n);
        hin = ho;
    }
    k_mlp<<<(n * (HIDDEN / 2) + 255) / 256, 256, 0, stream>>>(buf0, hin, consts, n * (HIDDEN / 2));

    hin = buf0;
    for (int i = 0; i < DEPTH; ++i) {
        __half* ho = (i & 1) ? bufB : bufA;
        k_conv<<<gConv, 256, 0, stream>>>(offs, ew, hin, buf0, ho, n);
        hin = ho;
    }
    k_cls<<<(n + 63) / 64, 256, 0, stream>>>(hin, Wcls, bcls, d_out, flag, n);
}